// Round 3
// baseline (84.443 us; speedup 1.0000x reference)
//
#include <hip/hip_runtime.h>

#define HW (512 * 512)
#define NCH 48              // L*C = 16*3 channels
#define BPC 32              // blocks per channel -> grid 1536 = 6/CU exactly
#define TPB 256
#define GRID (NCH * BPC)
#define ITERS (HW / 4 / (BPC * TPB))  // = 8, exact
#define V_EPS 1e-5

// Fused kernel: per-block partial sums of {e*e*m, c*e*m, c*c*m, m}; the last
// block to finish (device-scope counter) reduces all partials and writes the
// scalar loss. Deterministic: final reduction runs in one block, fixed order.
__global__ __launch_bounds__(TPB) void smse_fused(
    const float* __restrict__ correct,
    const float* __restrict__ estimate,
    const float* __restrict__ mask,
    float4* __restrict__ partials,        // [GRID]
    unsigned int* __restrict__ counter,   // zeroed by hipMemsetAsync each call
    float* __restrict__ out)
{
    const int ch  = blockIdx.x / BPC;
    const int bin = blockIdx.x % BPC;

    const float4* __restrict__ c4 = (const float4*)(correct  + (size_t)ch * HW);
    const float4* __restrict__ e4 = (const float4*)(estimate + (size_t)ch * HW);
    const float4* __restrict__ m4 = (const float4*)(mask     + (size_t)ch * HW);

    const int stride = BPC * TPB;  // 8192 float4
    int i = bin * TPB + threadIdx.x;

    float se2m = 0.f, scem = 0.f, sc2m = 0.f, sm = 0.f;
    #pragma unroll
    for (int it = 0; it < ITERS; ++it, i += stride) {
        float4 c = c4[i];
        float4 e = e4[i];
        float4 m = m4[i];
        float em;
        em = e.x * m.x; se2m += e.x * em; scem += c.x * em; sc2m += c.x * c.x * m.x; sm += m.x;
        em = e.y * m.y; se2m += e.y * em; scem += c.y * em; sc2m += c.y * c.y * m.y; sm += m.y;
        em = e.z * m.z; se2m += e.z * em; scem += c.z * em; sc2m += c.z * c.z * m.z; sm += m.z;
        em = e.w * m.w; se2m += e.w * em; scem += c.w * em; sc2m += c.w * c.w * m.w; sm += m.w;
    }

    // Wave64 butterfly reduce of the 4 accumulators.
    #pragma unroll
    for (int off = 32; off > 0; off >>= 1) {
        se2m += __shfl_down(se2m, off);
        scem += __shfl_down(scem, off);
        sc2m += __shfl_down(sc2m, off);
        sm   += __shfl_down(sm,   off);
    }

    __shared__ float4 red[TPB / 64];
    __shared__ unsigned int isLast;
    const int wave = threadIdx.x >> 6;
    const int lane = threadIdx.x & 63;
    if (lane == 0) red[wave] = make_float4(se2m, scem, sc2m, sm);
    __syncthreads();

    if (threadIdx.x == 0) {
        float4 s = red[0];
        #pragma unroll
        for (int w = 1; w < TPB / 64; ++w) {
            float4 r = red[w];
            s.x += r.x; s.y += r.y; s.z += r.z; s.w += r.w;
        }
        partials[(size_t)ch * BPC + bin] = s;
        __threadfence();  // release: make partial visible device-wide
        unsigned int old = atomicAdd(counter, 1u);  // device-scope by default
        isLast = (old == GRID - 1) ? 1u : 0u;
    }
    __syncthreads();

    if (isLast) {
        __threadfence();  // acquire: see all other blocks' partials
        const int t = threadIdx.x;
        float val = 0.f;
        if (t < NCH) {
            const float* p = (const float*)(partials + (size_t)t * BPC);
            double v = 0.0, num = 0.0, cc = 0.0, ms = 0.0;
            for (int b = 0; b < BPC; ++b) {
                float x0 = __hip_atomic_load(p + 4 * b + 0, __ATOMIC_RELAXED, __HIP_MEMORY_SCOPE_AGENT);
                float x1 = __hip_atomic_load(p + 4 * b + 1, __ATOMIC_RELAXED, __HIP_MEMORY_SCOPE_AGENT);
                float x2 = __hip_atomic_load(p + 4 * b + 2, __ATOMIC_RELAXED, __HIP_MEMORY_SCOPE_AGENT);
                float x3 = __hip_atomic_load(p + 4 * b + 3, __ATOMIC_RELAXED, __HIP_MEMORY_SCOPE_AGENT);
                v += x0; num += x1; cc += x2; ms += x3;
            }
            double alpha = (v > V_EPS) ? (num / v) : 0.0;
            double err = cc - alpha * (2.0 * num - alpha * v);
            val = (float)(err / ms);
        }
        if (t < 64) {  // single-wave reduce over the 48 channel values
            #pragma unroll
            for (int off = 32; off > 0; off >>= 1) val += __shfl_down(val, off);
            if (t == 0) out[0] = val / (float)NCH;
        }
    }
}

extern "C" void kernel_launch(void* const* d_in, const int* in_sizes, int n_in,
                              void* d_out, int out_size, void* d_ws, size_t ws_size,
                              hipStream_t stream) {
    const float* correct  = (const float*)d_in[0];
    const float* estimate = (const float*)d_in[1];
    const float* mask     = (const float*)d_in[2];
    float* out = (float*)d_out;

    float4* partials = (float4*)d_ws;                       // 1536 * 16 B = 24 KiB
    unsigned int* counter = (unsigned int*)((char*)d_ws + GRID * sizeof(float4));

    hipMemsetAsync(counter, 0, sizeof(unsigned int), stream);  // capture-safe memset node
    smse_fused<<<GRID, TPB, 0, stream>>>(correct, estimate, mask, partials, counter, out);
}

// Round 4
// 29.164 us; speedup vs baseline: 2.8955x; 2.8955x over previous
//
#include <hip/hip_runtime.h>

#define HW (512 * 512)
#define NCH 48              // L*C = 16*3 channels
#define BPC 32              // blocks per channel -> grid 1536 = 6/CU exactly
#define TPB 256
#define ITERS (HW / 4 / (BPC * TPB))  // = 8, exact
#define V_EPS 1e-5

// Kernel 1: per-block partial sums of {e*e*m, c*e*m, c*c*m, m} over one channel.
__global__ __launch_bounds__(TPB) void smse_partials(
    const float* __restrict__ correct,
    const float* __restrict__ estimate,
    const float* __restrict__ mask,
    float4* __restrict__ partials)  // [NCH * BPC]
{
    const int ch  = blockIdx.x / BPC;
    const int bin = blockIdx.x % BPC;

    const float4* __restrict__ c4 = (const float4*)(correct  + (size_t)ch * HW);
    const float4* __restrict__ e4 = (const float4*)(estimate + (size_t)ch * HW);
    const float4* __restrict__ m4 = (const float4*)(mask     + (size_t)ch * HW);

    const int stride = BPC * TPB;  // 8192 float4
    int i = bin * TPB + threadIdx.x;

    float se2m = 0.f, scem = 0.f, sc2m = 0.f, sm = 0.f;
    #pragma unroll
    for (int it = 0; it < ITERS; ++it, i += stride) {
        float4 c = c4[i];
        float4 e = e4[i];
        float4 m = m4[i];
        float em;
        em = e.x * m.x; se2m += e.x * em; scem += c.x * em; sc2m += c.x * c.x * m.x; sm += m.x;
        em = e.y * m.y; se2m += e.y * em; scem += c.y * em; sc2m += c.y * c.y * m.y; sm += m.y;
        em = e.z * m.z; se2m += e.z * em; scem += c.z * em; sc2m += c.z * c.z * m.z; sm += m.z;
        em = e.w * m.w; se2m += e.w * em; scem += c.w * em; sc2m += c.w * c.w * m.w; sm += m.w;
    }

    // Wave64 butterfly reduce of the 4 accumulators.
    #pragma unroll
    for (int off = 32; off > 0; off >>= 1) {
        se2m += __shfl_down(se2m, off);
        scem += __shfl_down(scem, off);
        sc2m += __shfl_down(sc2m, off);
        sm   += __shfl_down(sm,   off);
    }

    __shared__ float4 red[TPB / 64];
    const int wave = threadIdx.x >> 6;
    const int lane = threadIdx.x & 63;
    if (lane == 0) red[wave] = make_float4(se2m, scem, sc2m, sm);
    __syncthreads();

    if (threadIdx.x == 0) {
        float4 s = red[0];
        #pragma unroll
        for (int w = 1; w < TPB / 64; ++w) {
            float4 r = red[w];
            s.x += r.x; s.y += r.y; s.z += r.z; s.w += r.w;
        }
        partials[(size_t)ch * BPC + bin] = s;
    }
}

// Kernel 2: parallel reduce. 8 threads per channel, each loads 4 float4
// partials (issued in one burst), width-8 shuffle reduce, per-channel
// formula, then one wave reduces the 48 channel values.
__global__ __launch_bounds__(384) void smse_final(
    const float4* __restrict__ partials,
    float* __restrict__ out)
{
    const int t  = threadIdx.x;   // 384 = 48 channels * 8
    const int ch = t >> 3;
    const int k  = t & 7;

    // Burst-load this thread's 4 partials (independent L2-hit loads).
    const float4* p = partials + (size_t)ch * BPC + k * 4;
    float4 a = p[0], b = p[1], c = p[2], d = p[3];
    float sx = (a.x + b.x) + (c.x + d.x);
    float sy = (a.y + b.y) + (c.y + d.y);
    float sz = (a.z + b.z) + (c.z + d.z);
    float sw = (a.w + b.w) + (c.w + d.w);

    // Reduce across the 8 lanes of this channel (lanes are contiguous in-wave).
    #pragma unroll
    for (int off = 4; off > 0; off >>= 1) {
        sx += __shfl_down(sx, off, 8);
        sy += __shfl_down(sy, off, 8);
        sz += __shfl_down(sz, off, 8);
        sw += __shfl_down(sw, off, 8);
    }

    __shared__ float chval[64];
    if (t < 64) chval[t] = 0.f;
    __syncthreads();
    if (k == 0) {
        double v = sx, num = sy, cc = sz, ms = sw;
        double alpha = (v > V_EPS) ? (num / v) : 0.0;
        double err = cc - alpha * (2.0 * num - alpha * v);
        chval[ch] = (float)(err / ms);
    }
    __syncthreads();

    if (t < 64) {
        float val = chval[t];
        #pragma unroll
        for (int off = 32; off > 0; off >>= 1) val += __shfl_down(val, off);
        if (t == 0) out[0] = val / (float)NCH;
    }
}

extern "C" void kernel_launch(void* const* d_in, const int* in_sizes, int n_in,
                              void* d_out, int out_size, void* d_ws, size_t ws_size,
                              hipStream_t stream) {
    const float* correct  = (const float*)d_in[0];
    const float* estimate = (const float*)d_in[1];
    const float* mask     = (const float*)d_in[2];
    float* out = (float*)d_out;
    float4* partials = (float4*)d_ws;  // NCH*BPC float4 = 24 KiB

    smse_partials<<<NCH * BPC, TPB, 0, stream>>>(correct, estimate, mask, partials);
    smse_final<<<1, 384, 0, stream>>>(partials, out);
}